// Round 2
// baseline (614.593 us; speedup 1.0000x reference)
//
#include <hip/hip_runtime.h>
#include <hip/hip_bf16.h>

// LSTM decoder: 160000 independent tokens, 12 steps, F=64.
// Per block: 64 tokens, 4 waves. Transposed MFMA GEMMs (gates^T = W·H^T) with
// gate rows reordered r=4f+g so each lane's 4 acc regs = (i,f,g,o) of one (t,f).
// One barrier per step; yt B-frags are reused as next step's gate B-frags.

typedef float  f32x4  __attribute__((ext_vector_type(4)));
typedef short  bf16x8 __attribute__((ext_vector_type(8)));
typedef short  bf16x4 __attribute__((ext_vector_type(4)));

#define NTOK  160000
#define NSTEP 12
#define MTOK  64

__device__ __forceinline__ unsigned short f2bf(float x) {
  union { float f; unsigned u; } v; v.f = x;
  unsigned r = v.u + 0x7fffu + ((v.u >> 16) & 1u);   // RNE
  return (unsigned short)(r >> 16);
}
__device__ __forceinline__ float sigm(float x) {
  return __builtin_amdgcn_rcpf(1.0f + __builtin_amdgcn_exp2f(-1.4426950408889634f * x));
}
__device__ __forceinline__ float tanhx(float x) {
  // tanh(x) = 1 - 2/(1+e^{2x}); saturates correctly at +/-inf, no NaN.
  float t = __builtin_amdgcn_exp2f(2.8853900817779268f * x);
  return 1.0f - 2.0f * __builtin_amdgcn_rcpf(1.0f + t);
}

// swizzled LDS offset (ushort units) for H[t][f], 8-element-block XOR swizzle
__device__ __forceinline__ int hoff(int t, int f) {
  return t * 64 + ((((f >> 3) ^ (t & 7)) << 3) | (f & 7));
}

__global__ __launch_bounds__(256, 2)
void lstm_fused(const float* __restrict__ X,    // (160000, 64)
                const float* __restrict__ GW,   // (256, 128)  rows: [i;f;g;o] x 64
                const float* __restrict__ GB,   // (256)
                const float* __restrict__ WE,   // (64, 64)
                float* __restrict__ OUT)        // (12, 160000, 64)
{
  __shared__ alignas(16) unsigned short Hb[2][MTOK * 64];

  const int tid  = threadIdx.x;
  const int lane = tid & 63;
  const int w    = tid >> 6;     // wave 0..3: owns gate rows [64w,64w+64) and j in [16w,16w+16)
  const int l15  = lane & 15;
  const int l4   = lane >> 4;    // 0..3
  const long t0  = (long)blockIdx.x * MTOK;

  // ---- stage X tile into Hb[1] as swizzled bf16 ----
  {
    const int t  = tid >> 2;
    const int fb = (tid & 3) << 4;
    const float* xp = X + (size_t)(t0 + t) * 64 + fb;
    #pragma unroll
    for (int q = 0; q < 4; ++q) {
      const float4 v = *(const float4*)(xp + q * 4);
      const int f = fb + q * 4;
      bf16x4 p;
      p[0] = (short)f2bf(v.x); p[1] = (short)f2bf(v.y);
      p[2] = (short)f2bf(v.z); p[3] = (short)f2bf(v.w);
      *(bf16x4*)&Hb[1][hoff(t, f)] = p;
    }
  }

  // ---- persistent A-fragments ----
  // Wh (h-part of gate_w, cols 64..127), reordered rows r=4f+g.
  // A-frag: lane holds row (lane&15), k = (lane>>4)*8 + [0..8)
  bf16x8 whf[4][2];
  #pragma unroll
  for (int rt = 0; rt < 4; ++rt) {
    const int r = (w << 6) + (rt << 4) + l15;
    const int f = r >> 2, g = r & 3;
    const float* base = GW + (size_t)((g << 6) + f) * 128 + 64 + (l4 << 3);
    #pragma unroll
    for (int kb = 0; kb < 2; ++kb) {
      const float4 a = *(const float4*)(base + kb * 32);
      const float4 b = *(const float4*)(base + kb * 32 + 4);
      bf16x8 fr;
      fr[0]=(short)f2bf(a.x); fr[1]=(short)f2bf(a.y); fr[2]=(short)f2bf(a.z); fr[3]=(short)f2bf(a.w);
      fr[4]=(short)f2bf(b.x); fr[5]=(short)f2bf(b.y); fr[6]=(short)f2bf(b.z); fr[7]=(short)f2bf(b.w);
      whf[rt][kb] = fr;
    }
  }
  // W_edge^T as A: A[j][k]=WE[k][j], j = 16w + (lane&15)
  bf16x8 wef[2];
  {
    const int j = (w << 4) + l15;
    #pragma unroll
    for (int kb = 0; kb < 2; ++kb) {
      bf16x8 fr;
      #pragma unroll
      for (int jj = 0; jj < 8; ++jj)
        fr[jj] = (short)f2bf(WE[(kb * 32 + (l4 << 3) + jj) * 64 + j]);
      wef[kb] = fr;
    }
  }

  // ---- xg init with bias (D-layout: lane reg g at f = 16w+4rt+l4) ----
  f32x4 xg[4][4];
  #pragma unroll
  for (int rt = 0; rt < 4; ++rt) {
    const int f = (w << 4) + (rt << 2) + l4;
    f32x4 bv;
    #pragma unroll
    for (int g = 0; g < 4; ++g) bv[g] = GB[(g << 6) + f];
    #pragma unroll
    for (int ct = 0; ct < 4; ++ct) xg[rt][ct] = bv;
  }

  __syncthreads();

  // ---- xg += Wx · X^T (Wx frags transient) ----
  {
    bf16x8 bx[4][2];
    #pragma unroll
    for (int ct = 0; ct < 4; ++ct) {
      const int t = (ct << 4) + l15;
      #pragma unroll
      for (int kb = 0; kb < 2; ++kb)
        bx[ct][kb] = *(const bf16x8*)&Hb[1][t * 64 + ((((kb << 2) + l4) ^ (t & 7)) << 3)];
    }
    #pragma unroll
    for (int rt = 0; rt < 4; ++rt) {
      const int r = (w << 6) + (rt << 4) + l15;
      const int f = r >> 2, g = r & 3;
      const float* base = GW + (size_t)((g << 6) + f) * 128 + (l4 << 3);
      #pragma unroll
      for (int kb = 0; kb < 2; ++kb) {
        const float4 a = *(const float4*)(base + kb * 32);
        const float4 b = *(const float4*)(base + kb * 32 + 4);
        bf16x8 fr;
        fr[0]=(short)f2bf(a.x); fr[1]=(short)f2bf(a.y); fr[2]=(short)f2bf(a.z); fr[3]=(short)f2bf(a.w);
        fr[4]=(short)f2bf(b.x); fr[5]=(short)f2bf(b.y); fr[6]=(short)f2bf(b.z); fr[7]=(short)f2bf(b.w);
        #pragma unroll
        for (int ct = 0; ct < 4; ++ct)
          xg[rt][ct] = __builtin_amdgcn_mfma_f32_16x16x32_bf16(fr, bx[ct][kb], xg[rt][ct], 0, 0, 0);
      }
    }
  }
  __syncthreads();   // all waves done reading Hb[1] (X) before it can be reused

  float c[4][4];
  #pragma unroll
  for (int rt = 0; rt < 4; ++rt)
    #pragma unroll
    for (int ct = 0; ct < 4; ++ct) c[rt][ct] = 0.0f;

  // h(0) = 0: start with zero B-frags, no LDS read needed.
  bf16x8 bh[4][2];
  #pragma unroll
  for (int ct = 0; ct < 4; ++ct)
    #pragma unroll
    for (int kb = 0; kb < 2; ++kb)
      bh[ct][kb] = (bf16x8)0;

  int buf = 0;   // step-0 h goes to Hb[0] (X in Hb[1] already consumed)
  for (int s = 0; s < NSTEP; ++s) {
    // gates^T = Wh·H^T + xg ; immediate elementwise LSTM update
    #pragma unroll
    for (int rt = 0; rt < 4; ++rt) {
      #pragma unroll
      for (int ct = 0; ct < 4; ++ct) {
        f32x4 acc = __builtin_amdgcn_mfma_f32_16x16x32_bf16(whf[rt][0], bh[ct][0], xg[rt][ct], 0, 0, 0);
        acc = __builtin_amdgcn_mfma_f32_16x16x32_bf16(whf[rt][1], bh[ct][1], acc, 0, 0, 0);
        const float ig = sigm(acc[0]);
        const float fg = sigm(acc[1]);
        const float gg = tanhx(acc[2]);
        const float og = sigm(acc[3]);
        const float cn = fg * c[rt][ct] + ig * gg;
        c[rt][ct] = cn;
        const float h = og * tanhx(cn);
        const int t = (ct << 4) + l15;
        const int f = (w << 4) + (rt << 2) + l4;
        Hb[buf][hoff(t, f)] = f2bf(h);
      }
    }
    __syncthreads();   // h(s) visible to all waves

    // read h(s) frags once: used by yt NOW and as gate B-frags next step
    #pragma unroll
    for (int ct = 0; ct < 4; ++ct) {
      const int t = (ct << 4) + l15;
      #pragma unroll
      for (int kb = 0; kb < 2; ++kb)
        bh[ct][kb] = *(const bf16x8*)&Hb[buf][t * 64 + ((((kb << 2) + l4) ^ (t & 7)) << 3)];
    }

    // yt^T = sigmoid(WE^T · H^T), coalesced float4 stores (4 consecutive j/lane)
    #pragma unroll
    for (int ct = 0; ct < 4; ++ct) {
      f32x4 y = {0.f, 0.f, 0.f, 0.f};
      y = __builtin_amdgcn_mfma_f32_16x16x32_bf16(wef[0], bh[ct][0], y, 0, 0, 0);
      y = __builtin_amdgcn_mfma_f32_16x16x32_bf16(wef[1], bh[ct][1], y, 0, 0, 0);
      float4 o;
      o.x = sigm(y[0]); o.y = sigm(y[1]); o.z = sigm(y[2]); o.w = sigm(y[3]);
      const int t = (ct << 4) + l15;
      float* op = OUT + ((size_t)s * NTOK + (size_t)(t0 + t)) * 64 + ((w << 4) + (l4 << 2));
      *(float4*)op = o;
    }
    buf ^= 1;
  }
}

extern "C" void kernel_launch(void* const* d_in, const int* in_sizes, int n_in,
                              void* d_out, int out_size, void* d_ws, size_t ws_size,
                              hipStream_t stream) {
  (void)in_sizes; (void)n_in; (void)out_size; (void)d_ws; (void)ws_size;
  const float* x  = (const float*)d_in[0];
  const float* gw = (const float*)d_in[1];
  const float* gb = (const float*)d_in[2];
  const float* we = (const float*)d_in[3];
  float* out = (float*)d_out;
  hipLaunchKernelGGL(lstm_fused, dim3(NTOK / MTOK), dim3(256), 0, stream,
                     x, gw, gb, we, out);
}